// Round 11
// baseline (495.870 us; speedup 1.0000x reference)
//
#include <hip/hip_runtime.h>
#include <math.h>

#define NR 4096
#define DD 512
#define MM 50000
#define CAP 640
#define TK 64
#define T0 0.118f
#define QS 400.0f
#define QINV (1.0f / 160000.0f)

typedef unsigned int u32;
typedef unsigned short u16;
typedef int i32x4 __attribute__((ext_vector_type(4)));

#define AS1 __attribute__((address_space(1)))
#define AS3 __attribute__((address_space(3)))

__device__ __forceinline__ u16 f2bf(float f) {
    u32 u = __float_as_uint(f);
    u32 r = (u + 0x7FFFu + ((u >> 16) & 1u)) >> 16;   // RNE
    return (u16)r;
}

// ---------------- ws layout ----------------
// [0,16384)                cnt (4096 u32)  -- zeroed each launch
// [16384,20480)            geom partials (1024 f32, fully written)
// [32768,32772)            e_geom scalar
// [65536, +2MB)            xi8  (4096x512 int8, scale 400)
// [+2MB, +27.6MB)          mui8 (50000x512 int8)
// [+27.6MB, +38.1MB)       cand keys (4096 x 640 u32 = {bf16val:16, idx:16})

// ============ int8 symmetric quantization (RNE, scale 400) ============
__global__ __launch_bounds__(256) void k_quant(const float* __restrict__ src,
                                               char* __restrict__ dst, int n8) {
    int i = blockIdx.x * 256 + threadIdx.x;
    if (i >= n8) return;
    const float4* s4 = (const float4*)src;
    float4 a = s4[(size_t)i * 2], b = s4[(size_t)i * 2 + 1];
    float v[8] = {a.x, a.y, a.z, a.w, b.x, b.y, b.z, b.w};
    u32 lo = 0, hi = 0;
#pragma unroll
    for (int j = 0; j < 4; ++j) {
        int q = __float2int_rn(v[j] * QS);
        q = q > 127 ? 127 : (q < -127 ? -127 : q);
        lo |= ((u32)(unsigned char)(char)q) << (8 * j);
    }
#pragma unroll
    for (int j = 0; j < 4; ++j) {
        int q = __float2int_rn(v[4 + j] * QS);
        q = q > 127 ? 127 : (q < -127 ? -127 : q);
        hi |= ((u32)(unsigned char)(char)q) << (8 * j);
    }
    *(uint2*)(dst + (size_t)i * 8) = make_uint2(lo, hi);
}

// ============ i8 MFMA GEMM x @ mu^T, 128x128 tile, threshold push ============
// LDS-BW fix: A fragments loaded DIRECTLY global->VGPR (x is 2 MB, L2-hot);
// only B (mu, streamed) goes through LDS (16 KB, zero-conflict swizzle).
// LDS bytes/tile: 96 KB -> 48 KB => MfmaUtil ceiling ~21% -> ~42%.
__global__ __launch_bounds__(256, 4) void k_gemm_topk(
    const char* __restrict__ xi8, const char* __restrict__ mui8,
    u32* __restrict__ cnt, u32* __restrict__ cand)
{
    __shared__ char smem[16384];          // B tile only: 128 rows x 128 B

    const int t = threadIdx.x;
    const int lane = t & 63;
    const int wid = t >> 6;
    const int wr = wid >> 1, wc = wid & 1;
    const int fr = lane & 15, fq = lane >> 4;

    // ---- XCD-aware bijective remap (12512 blocks = 8 x 1564) ----
    const u32 d   = (u32)blockIdx.y * (u32)gridDim.x + (u32)blockIdx.x;
    const u32 xcd = d & 7u;
    const u32 p   = xcd * 1564u + (d >> 3);
    const int r0  = (int)(p & 31u) * 128;     // row-panel (fastest)
    const int c0  = (int)(p >> 5) * 128;      // col-panel

    i32x4 acc[4][4];
#pragma unroll
    for (int m = 0; m < 4; ++m)
#pragma unroll
        for (int n = 0; n < 4; ++n) acc[m][n] = (i32x4){0, 0, 0, 0};

    // per-lane A row base: row r0 + wr*64 + fr, advance m by 16 rows (8192 B)
    const char* aBase = xi8 + (size_t)(r0 + wr * 64 + fr) * DD + fq * 16;

    for (int kt = 0; kt < DD; kt += 128) {
        __syncthreads();                  // previous B tile fully consumed
        // stage B (mu) -> LDS, 4 x 16B per thread
#pragma unroll
        for (int i = 0; i < 4; ++i) {
            const int L  = i * 4096 + t * 16;
            const int rw = L >> 7;                 // 0..127 (128-B rows)
            const int cb = (L & 127) ^ ((rw & 7) << 4);
            int gr = c0 + rw; if (gr > MM - 1) gr = MM - 1;   // clamp, filtered at push
            const char* srcB = mui8 + (size_t)gr * DD + kt + cb;
            __builtin_amdgcn_global_load_lds((const AS1 u32*)srcB, (AS3 u32*)(smem + L), 16, 0, 0);
        }
        // A fragments direct global->reg (L2-hot), 8 x 16B per thread
        i32x4 Ar[2][4];
#pragma unroll
        for (int kk = 0; kk < 2; ++kk)
#pragma unroll
            for (int m = 0; m < 4; ++m)
                Ar[kk][m] = *(const i32x4*)(aBase + (size_t)m * (16 * DD) + kt + kk * 64);
        __syncthreads();                  // B visible, A loaded (vmcnt drained)
#pragma unroll
        for (int kk = 0; kk < 2; ++kk) {  // two K=64 halves of BK=128
            i32x4 bfr[4];
#pragma unroll
            for (int n = 0; n < 4; ++n) {
                const int rb = wc * 64 + n * 16 + fr;
                bfr[n] = *(const i32x4*)(smem + ((rb << 7) | ((kk * 64 + fq * 16) ^ ((rb & 7) << 4))));
            }
#pragma unroll
            for (int m = 0; m < 4; ++m)
#pragma unroll
                for (int n = 0; n < 4; ++n)
                    acc[m][n] = __builtin_amdgcn_mfma_i32_16x16x64_i8(Ar[kk][m], bfr[n], acc[m][n], 0, 0, 0);
        }
    }

    // C/D layout (m89): col = lane&15, row = (lane>>4)*4 + reg
#pragma unroll
    for (int m = 0; m < 4; ++m) {
        const int rowb = r0 + wr * 64 + m * 16 + fq * 4;
#pragma unroll
        for (int n = 0; n < 4; ++n) {
            const int col = c0 + wc * 64 + n * 16 + fr;
#pragma unroll
            for (int r = 0; r < 4; ++r) {
                const float v = (float)acc[m][n][r] * QINV;
                if (v >= T0 && col < MM) {
                    u32 pos = atomicAdd(&cnt[rowb + r], 1u);
                    if (pos < CAP)
                        cand[(size_t)(rowb + r) * CAP + pos] =
                            (((u32)f2bf(v)) << 16) | (u32)col;
                }
            }
        }
    }
}

// ============ x @ x^T geometric energy (same A-direct structure) ============
__global__ __launch_bounds__(256, 4) void k_geom(
    const char* __restrict__ xi8, float* __restrict__ partial)
{
    const int bx = blockIdx.x, by = blockIdx.y;
    const int t = threadIdx.x;
    if (bx < by) { if (t == 0) partial[by * 32 + bx] = 0.f; return; }

    __shared__ char smem[16384];
    __shared__ float red[4];

    const int lane = t & 63;
    const int wid = t >> 6;
    const int wr = wid >> 1, wc = wid & 1;
    const int fr = lane & 15, fq = lane >> 4;
    const int r0 = by * 128;
    const int c0 = bx * 128;

    i32x4 acc[4][4];
#pragma unroll
    for (int m = 0; m < 4; ++m)
#pragma unroll
        for (int n = 0; n < 4; ++n) acc[m][n] = (i32x4){0, 0, 0, 0};

    const char* aBase = xi8 + (size_t)(r0 + wr * 64 + fr) * DD + fq * 16;

    for (int kt = 0; kt < DD; kt += 128) {
        __syncthreads();
#pragma unroll
        for (int i = 0; i < 4; ++i) {
            const int L  = i * 4096 + t * 16;
            const int rw = L >> 7;
            const int cb = (L & 127) ^ ((rw & 7) << 4);
            const char* srcB = xi8 + (size_t)(c0 + rw) * DD + kt + cb;
            __builtin_amdgcn_global_load_lds((const AS1 u32*)srcB, (AS3 u32*)(smem + L), 16, 0, 0);
        }
        i32x4 Ar[2][4];
#pragma unroll
        for (int kk = 0; kk < 2; ++kk)
#pragma unroll
            for (int m = 0; m < 4; ++m)
                Ar[kk][m] = *(const i32x4*)(aBase + (size_t)m * (16 * DD) + kt + kk * 64);
        __syncthreads();
#pragma unroll
        for (int kk = 0; kk < 2; ++kk) {
            i32x4 bfr[4];
#pragma unroll
            for (int n = 0; n < 4; ++n) {
                const int rb = wc * 64 + n * 16 + fr;
                bfr[n] = *(const i32x4*)(smem + ((rb << 7) | ((kk * 64 + fq * 16) ^ ((rb & 7) << 4))));
            }
#pragma unroll
            for (int m = 0; m < 4; ++m)
#pragma unroll
                for (int n = 0; n < 4; ++n)
                    acc[m][n] = __builtin_amdgcn_mfma_i32_16x16x64_i8(Ar[kk][m], bfr[n], acc[m][n], 0, 0, 0);
        }
    }

    float local = 0.f;
#pragma unroll
    for (int m = 0; m < 4; ++m) {
        const int rowb = r0 + wr * 64 + m * 16 + fq * 4;
#pragma unroll
        for (int n = 0; n < 4; ++n) {
            const int col = c0 + wc * 64 + n * 16 + fr;
#pragma unroll
            for (int r = 0; r < 4; ++r) {
                if (rowb + r != col) {
                    float s = fminf((float)acc[m][n][r] * QINV, 0.9999f);
                    local += -logf(1.0f - s + 1e-4f);
                }
            }
        }
    }
    if (bx > by) local *= 2.f;   // symmetric half counted twice

#pragma unroll
    for (int off = 32; off >= 1; off >>= 1) local += __shfl_xor(local, off, 64);
    if (lane == 0) red[wid] = local;
    __syncthreads();
    if (t == 0) partial[by * 32 + bx] = red[0] + red[1] + red[2] + red[3];
}

__global__ void k_reduce_geom(const float* __restrict__ partial, float* __restrict__ egeom)
{
    __shared__ float red[16];
    const int t = threadIdx.x;
    float v = partial[t];
#pragma unroll
    for (int off = 32; off >= 1; off >>= 1) v += __shfl_xor(v, off, 64);
    const int wave = t >> 6, lane = t & 63;
    if (lane == 0) red[wave] = v;
    __syncthreads();
    if (t == 0) {
        float s = 0.f;
        for (int i = 0; i < 16; ++i) s += red[i];
        egeom[0] = s / ((float)NR * (float)(NR - 1));
    }
}

// ===== finalize: 1 wave per row. top-64 by key -> exact fp32 -> epilogue =====
__global__ __launch_bounds__(64) void k_finalize(
    const u32* __restrict__ cand, const u32* __restrict__ cnt,
    const float* __restrict__ x, const float* __restrict__ mu,
    const float* __restrict__ alpha, const float* __restrict__ kappa,
    const float* __restrict__ Ww, const float* __restrict__ Wb,
    const float* __restrict__ egeom, float* __restrict__ out)
{
    __shared__ u32   keys[CAP];
    __shared__ int   selid[TK];
    __shared__ float selex[TK];

    const int lane = threadIdx.x;
    const int row = blockIdx.x;
    const int cn = (int)cnt[row];
    const int c = cn < CAP ? cn : CAP;

    for (int s = lane; s < c; s += 64)
        keys[s] = cand[(size_t)row * CAP + s];
    __syncthreads();

    // iterative argmax: top-TK keys (value-major; distinct idx => no ties)
    for (int k = 0; k < TK; ++k) {
        u32 best = 0u; int bpos = -1;
        for (int s = lane; s < c; s += 64) {
            u32 v = keys[s];
            if (v > best) { best = v; bpos = s; }
        }
#pragma unroll
        for (int off = 32; off >= 1; off >>= 1) {
            u32 v2 = __shfl_xor(best, off, 64);
            int p2 = __shfl_xor(bpos, off, 64);
            if (v2 > best) { best = v2; bpos = p2; }
        }
        if (lane == 0) {
            selid[k] = (bpos >= 0) ? (int)(best & 0xFFFFu) : -1;
            if (bpos >= 0) keys[bpos] = 0u;
        }
        __syncthreads();
    }

    // exact fp32 dots for the TK selected candidates (batched 4-wide)
    float xr[8];
    {
        const float4* xp = (const float4*)(x + (size_t)row * DD);
        float4 a = xp[lane * 2], b = xp[lane * 2 + 1];
        xr[0] = a.x; xr[1] = a.y; xr[2] = a.z; xr[3] = a.w;
        xr[4] = b.x; xr[5] = b.y; xr[6] = b.z; xr[7] = b.w;
    }
    for (int s0 = 0; s0 < TK; s0 += 4) {
        int idv[4];
        float4 a0[4], a1[4];
#pragma unroll
        for (int j = 0; j < 4; ++j) {
            idv[j] = selid[s0 + j];                    // wave-uniform
            const int rid = idv[j] >= 0 ? idv[j] : 0;
            const float4* mp = (const float4*)(mu + (size_t)rid * DD);
            a0[j] = mp[lane * 2];
            a1[j] = mp[lane * 2 + 1];
        }
        float d[4];
#pragma unroll
        for (int j = 0; j < 4; ++j)
            d[j] = xr[0] * a0[j].x + xr[1] * a0[j].y + xr[2] * a0[j].z + xr[3] * a0[j].w
                 + xr[4] * a1[j].x + xr[5] * a1[j].y + xr[6] * a1[j].z + xr[7] * a1[j].w;
#pragma unroll
        for (int j = 0; j < 4; ++j) {
#pragma unroll
            for (int off = 32; off >= 1; off >>= 1) d[j] += __shfl_xor(d[j], off, 64);
            if (lane == 0) selex[s0 + j] = (idv[j] >= 0) ? d[j] : -INFINITY;
        }
    }
    __syncthreads();

    float v = selex[lane];
    const int id = selid[lane];
    bool alive = (id >= 0);

    // drop the 32 smallest exact values -> exact top-32 remains
    for (int rdrop = 0; rdrop < 32; ++rdrop) {
        float mn = alive ? v : INFINITY;
        int  mp2 = alive ? lane : 64;
#pragma unroll
        for (int off = 32; off >= 1; off >>= 1) {
            float m2 = __shfl_xor(mn, off, 64);
            int   p2 = __shfl_xor(mp2, off, 64);
            if (m2 < mn || (m2 == mn && p2 < mp2)) { mn = m2; mp2 = p2; }
        }
        if (lane == mp2) alive = false;
    }

    const float dv = alive ? v : -INFINITY;

    // top-1 / top-2 exact values (u, v of the reference)
    float m1 = dv; int p1 = alive ? lane : 64;
#pragma unroll
    for (int off = 32; off >= 1; off >>= 1) {
        float m2 = __shfl_xor(m1, off, 64);
        int   p2 = __shfl_xor(p1, off, 64);
        if (m2 > m1 || (m2 == m1 && p2 < p1)) { m1 = m2; p1 = p2; }
    }
    const float uu = m1;
    float s1 = (lane == p1) ? -INFINITY : dv;
#pragma unroll
    for (int off = 32; off >= 1; off >>= 1) s1 = fmaxf(s1, __shfl_xor(s1, off, 64));
    const float vv = s1;

    const int gid = alive ? id : 0;
    const float av = alpha[gid];
    const float kv = kappa[gid];
    float imp = alive ? fmaxf(kv, 1e-4f) : 0.f;
    float simp = imp;
#pragma unroll
    for (int off = 32; off >= 1; off >>= 1) simp += __shfl_xor(simp, off, 64);
    float w = fmaxf(imp / simp, 1e-8f);
    float tk = alive ? (av * (dv - 1.0f) * 10.0f + logf(w)) : -INFINITY;
    float mx = tk;
#pragma unroll
    for (int off = 32; off >= 1; off >>= 1) mx = fmaxf(mx, __shfl_xor(mx, off, 64));
    float se = alive ? expf(tk - mx) : 0.f;
#pragma unroll
    for (int off = 32; off >= 1; off >>= 1) se += __shfl_xor(se, off, 64);

    if (lane == 0) {
        float esplat = -(mx + logf(se));
        float z = Ww[0] * uu + Ww[1] * vv + Ww[2] * uu * vv + Wb[0];
        float ecomp = 1.f / (1.f + expf(-z));
        out[row] = esplat + 0.1f * egeom[0] + 0.1f * ecomp;
    }
}

extern "C" void kernel_launch(void* const* d_in, const int* in_sizes, int n_in,
                              void* d_out, int out_size, void* d_ws, size_t ws_size,
                              hipStream_t stream)
{
    const float* x     = (const float*)d_in[0];
    const float* mu    = (const float*)d_in[1];
    const float* alpha = (const float*)d_in[2];
    const float* kappa = (const float*)d_in[3];
    const float* Ww    = (const float*)d_in[4];
    const float* Wb    = (const float*)d_in[5];
    float* out = (float*)d_out;

    char* ws = (char*)d_ws;
    u32*   cnt     = (u32*)ws;
    float* partial = (float*)(ws + 16384);
    float* egeom   = (float*)(ws + 32768);
    char*  xi8     = (char*)(ws + 65536);
    char*  mui8    = (char*)(ws + 65536 + 2097152);
    u32*   cand    = (u32*)(ws + 65536 + 2097152 + 25600000);

    hipMemsetAsync(cnt, 0, NR * sizeof(u32), stream);

    k_quant<<<(NR * DD / 8 + 255) / 256, 256, 0, stream>>>(x, xi8, NR * DD / 8);
    k_quant<<<(MM * DD / 8 + 255) / 256, 256, 0, stream>>>(mu, mui8, MM * DD / 8);

    dim3 g1(NR / 128, (MM + 127) / 128);   // 32 x 391 = 12512 = 8 x 1564
    k_gemm_topk<<<g1, 256, 0, stream>>>(xi8, mui8, cnt, cand);

    dim3 g2(32, 32);
    k_geom<<<g2, 256, 0, stream>>>(xi8, partial);

    k_reduce_geom<<<1, 1024, 0, stream>>>(partial, egeom);

    k_finalize<<<NR, 64, 0, stream>>>(cand, cnt, x, mu, alpha, kappa, Ww, Wb, egeom, out);
}

// Round 12
// 462.922 us; speedup vs baseline: 1.0712x; 1.0712x over previous
//
#include <hip/hip_runtime.h>
#include <math.h>

#define NR 4096
#define DD 512
#define MM 50000
#define CAP 640
#define TK 64
#define T0 0.118f
#define QS 400.0f
#define QINV (1.0f / 160000.0f)

typedef unsigned int u32;
typedef unsigned short u16;
typedef int i32x4 __attribute__((ext_vector_type(4)));

#define AS1 __attribute__((address_space(1)))
#define AS3 __attribute__((address_space(3)))

__device__ __forceinline__ u16 f2bf(float f) {
    u32 u = __float_as_uint(f);
    u32 r = (u + 0x7FFFu + ((u >> 16) & 1u)) >> 16;   // RNE
    return (u16)r;
}

// ---------------- ws layout ----------------
// [0,16384)                cnt (4096 u32)  -- zeroed each launch
// [16384,20480)            geom partials (1024 f32, fully written)
// [32768,32772)            e_geom scalar
// [65536, +2MB)            xi8  (4096x512 int8, scale 400)
// [+2MB, +27.6MB)          mui8 (50000x512 int8)
// [+27.6MB, +38.1MB)       cand keys (4096 x 640 u32 = {bf16val:16, idx:16})

// ============ int8 symmetric quantization (RNE, scale 400) ============
__global__ __launch_bounds__(256) void k_quant(const float* __restrict__ src,
                                               char* __restrict__ dst, int n8) {
    int i = blockIdx.x * 256 + threadIdx.x;
    if (i >= n8) return;
    const float4* s4 = (const float4*)src;
    float4 a = s4[(size_t)i * 2], b = s4[(size_t)i * 2 + 1];
    float v[8] = {a.x, a.y, a.z, a.w, b.x, b.y, b.z, b.w};
    u32 lo = 0, hi = 0;
#pragma unroll
    for (int j = 0; j < 4; ++j) {
        int q = __float2int_rn(v[j] * QS);
        q = q > 127 ? 127 : (q < -127 ? -127 : q);
        lo |= ((u32)(unsigned char)(char)q) << (8 * j);
    }
#pragma unroll
    for (int j = 0; j < 4; ++j) {
        int q = __float2int_rn(v[4 + j] * QS);
        q = q > 127 ? 127 : (q < -127 ? -127 : q);
        hi |= ((u32)(unsigned char)(char)q) << (8 * j);
    }
    *(uint2*)(dst + (size_t)i * 8) = make_uint2(lo, hi);
}

// ============ i8 MFMA GEMM x @ mu^T, 256x256 tile, threshold push ============
// Byte-bound fix: 256^2 tile halves total staged bytes (1.64 GB -> 820 MB).
// Schedule = R9/R10's proven plain 2-syncthreads per K-tile, SINGLE 64 KB
// buffer -> 2 blocks/CU co-residency covers the stage stall.
// 512 thr, 8 waves (2M x 4N), acc[8][4].
__global__ __launch_bounds__(512, 2) void k_gemm_topk(
    const char* __restrict__ xi8, const char* __restrict__ mui8,
    u32* __restrict__ cnt, u32* __restrict__ cand)
{
    __shared__ char smem[65536];          // A[256][128] | B[256][128]

    const int t = threadIdx.x;
    const int lane = t & 63;
    const int wid = t >> 6;               // 0..7
    const int wr = wid >> 2, wc = wid & 3;
    const int fr = lane & 15, fq = lane >> 4;

    // ---- XCD-aware bijective remap (3136 blocks = 8 x 392) ----
    const u32 d   = (u32)blockIdx.y * (u32)gridDim.x + (u32)blockIdx.x;
    const u32 xcd = d & 7u;
    const u32 p   = xcd * 392u + (d >> 3);
    const int r0  = (int)(p & 15u) * 256;     // row-panel (fastest)
    const int c0  = (int)(p >> 4) * 256;      // col-panel

    i32x4 acc[8][4];
#pragma unroll
    for (int m = 0; m < 8; ++m)
#pragma unroll
        for (int n = 0; n < 4; ++n) acc[m][n] = (i32x4){0, 0, 0, 0};

    for (int kt = 0; kt < DD; kt += 128) {
        __syncthreads();                  // previous tile fully consumed
#pragma unroll
        for (int i = 0; i < 4; ++i) {
            const int L  = i * 8192 + t * 16;
            const int rw = L >> 7;                 // 0..255 (128-B rows)
            const int cb = (L & 127) ^ ((rw & 7) << 4);
            const char* srcA = xi8 + (size_t)(r0 + rw) * DD + kt + cb;
            __builtin_amdgcn_global_load_lds((const AS1 u32*)srcA, (AS3 u32*)(smem + L), 16, 0, 0);
            int gr = c0 + rw; if (gr > MM - 1) gr = MM - 1;   // clamp, filtered at push
            const char* srcB = mui8 + (size_t)gr * DD + kt + cb;
            __builtin_amdgcn_global_load_lds((const AS1 u32*)srcB, (AS3 u32*)(smem + 32768 + L), 16, 0, 0);
        }
        __syncthreads();                  // staged tile visible (vmcnt drained)
#pragma unroll
        for (int kk = 0; kk < 2; ++kk) {  // two K=64 halves of BK=128
            i32x4 af[8], bfr[4];
#pragma unroll
            for (int m = 0; m < 8; ++m) {
                const int ra = wr * 128 + m * 16 + fr;
                af[m] = *(const i32x4*)(smem + ((ra << 7) | ((kk * 64 + fq * 16) ^ ((ra & 7) << 4))));
            }
#pragma unroll
            for (int n = 0; n < 4; ++n) {
                const int rb = wc * 64 + n * 16 + fr;
                bfr[n] = *(const i32x4*)(smem + 32768 + ((rb << 7) | ((kk * 64 + fq * 16) ^ ((rb & 7) << 4))));
            }
#pragma unroll
            for (int m = 0; m < 8; ++m)
#pragma unroll
                for (int n = 0; n < 4; ++n)
                    acc[m][n] = __builtin_amdgcn_mfma_i32_16x16x64_i8(af[m], bfr[n], acc[m][n], 0, 0, 0);
        }
    }

    // C/D layout (m89): col = lane&15, row = (lane>>4)*4 + reg
#pragma unroll
    for (int m = 0; m < 8; ++m) {
        const int rowb = r0 + wr * 128 + m * 16 + fq * 4;
#pragma unroll
        for (int n = 0; n < 4; ++n) {
            const int col = c0 + wc * 64 + n * 16 + fr;
#pragma unroll
            for (int r = 0; r < 4; ++r) {
                const float v = (float)acc[m][n][r] * QINV;
                if (v >= T0 && col < MM) {
                    u32 pos = atomicAdd(&cnt[rowb + r], 1u);
                    if (pos < CAP)
                        cand[(size_t)(rowb + r) * CAP + pos] =
                            (((u32)f2bf(v)) << 16) | (u32)col;
                }
            }
        }
    }
}

// ============ x @ x^T geometric energy (R10's proven 128^2 form) ============
__global__ __launch_bounds__(256, 5) void k_geom(
    const char* __restrict__ xi8, float* __restrict__ partial)
{
    const int bx = blockIdx.x, by = blockIdx.y;
    const int t = threadIdx.x;
    if (bx < by) { if (t == 0) partial[by * 32 + bx] = 0.f; return; }

    __shared__ char smem[32768];
    __shared__ float red[4];

    const int lane = t & 63;
    const int wid = t >> 6;
    const int wr = wid >> 1, wc = wid & 1;
    const int fr = lane & 15, fq = lane >> 4;
    const int r0 = by * 128;
    const int c0 = bx * 128;

    i32x4 acc[4][4];
#pragma unroll
    for (int m = 0; m < 4; ++m)
#pragma unroll
        for (int n = 0; n < 4; ++n) acc[m][n] = (i32x4){0, 0, 0, 0};

    for (int kt = 0; kt < DD; kt += 128) {
        __syncthreads();
#pragma unroll
        for (int i = 0; i < 4; ++i) {
            const int L  = i * 4096 + t * 16;
            const int rw = L >> 7;
            const int cb = (L & 127) ^ ((rw & 7) << 4);
            const char* srcA = xi8 + (size_t)(r0 + rw) * DD + kt + cb;
            __builtin_amdgcn_global_load_lds((const AS1 u32*)srcA, (AS3 u32*)(smem + L), 16, 0, 0);
            const char* srcB = xi8 + (size_t)(c0 + rw) * DD + kt + cb;
            __builtin_amdgcn_global_load_lds((const AS1 u32*)srcB, (AS3 u32*)(smem + 16384 + L), 16, 0, 0);
        }
        __syncthreads();
#pragma unroll
        for (int kk = 0; kk < 2; ++kk) {
            i32x4 af[4], bfr[4];
#pragma unroll
            for (int m = 0; m < 4; ++m) {
                const int ra = wr * 64 + m * 16 + fr;
                af[m] = *(const i32x4*)(smem + ((ra << 7) | ((kk * 64 + fq * 16) ^ ((ra & 7) << 4))));
            }
#pragma unroll
            for (int n = 0; n < 4; ++n) {
                const int rb = wc * 64 + n * 16 + fr;
                bfr[n] = *(const i32x4*)(smem + 16384 + ((rb << 7) | ((kk * 64 + fq * 16) ^ ((rb & 7) << 4))));
            }
#pragma unroll
            for (int m = 0; m < 4; ++m)
#pragma unroll
                for (int n = 0; n < 4; ++n)
                    acc[m][n] = __builtin_amdgcn_mfma_i32_16x16x64_i8(af[m], bfr[n], acc[m][n], 0, 0, 0);
        }
    }

    float local = 0.f;
#pragma unroll
    for (int m = 0; m < 4; ++m) {
        const int rowb = r0 + wr * 64 + m * 16 + fq * 4;
#pragma unroll
        for (int n = 0; n < 4; ++n) {
            const int col = c0 + wc * 64 + n * 16 + fr;
#pragma unroll
            for (int r = 0; r < 4; ++r) {
                if (rowb + r != col) {
                    float s = fminf((float)acc[m][n][r] * QINV, 0.9999f);
                    local += -logf(1.0f - s + 1e-4f);
                }
            }
        }
    }
    if (bx > by) local *= 2.f;   // symmetric half counted twice

#pragma unroll
    for (int off = 32; off >= 1; off >>= 1) local += __shfl_xor(local, off, 64);
    if (lane == 0) red[wid] = local;
    __syncthreads();
    if (t == 0) partial[by * 32 + bx] = red[0] + red[1] + red[2] + red[3];
}

__global__ void k_reduce_geom(const float* __restrict__ partial, float* __restrict__ egeom)
{
    __shared__ float red[16];
    const int t = threadIdx.x;
    float v = partial[t];
#pragma unroll
    for (int off = 32; off >= 1; off >>= 1) v += __shfl_xor(v, off, 64);
    const int wave = t >> 6, lane = t & 63;
    if (lane == 0) red[wave] = v;
    __syncthreads();
    if (t == 0) {
        float s = 0.f;
        for (int i = 0; i < 16; ++i) s += red[i];
        egeom[0] = s / ((float)NR * (float)(NR - 1));
    }
}

// ===== finalize: 1 wave per row. top-64 by key -> exact fp32 -> epilogue =====
__global__ __launch_bounds__(64) void k_finalize(
    const u32* __restrict__ cand, const u32* __restrict__ cnt,
    const float* __restrict__ x, const float* __restrict__ mu,
    const float* __restrict__ alpha, const float* __restrict__ kappa,
    const float* __restrict__ Ww, const float* __restrict__ Wb,
    const float* __restrict__ egeom, float* __restrict__ out)
{
    __shared__ u32   keys[CAP];
    __shared__ int   selid[TK];
    __shared__ float selex[TK];

    const int lane = threadIdx.x;
    const int row = blockIdx.x;
    const int cn = (int)cnt[row];
    const int c = cn < CAP ? cn : CAP;

    for (int s = lane; s < c; s += 64)
        keys[s] = cand[(size_t)row * CAP + s];
    __syncthreads();

    // iterative argmax: top-TK keys (value-major; distinct idx => no ties)
    for (int k = 0; k < TK; ++k) {
        u32 best = 0u; int bpos = -1;
        for (int s = lane; s < c; s += 64) {
            u32 v = keys[s];
            if (v > best) { best = v; bpos = s; }
        }
#pragma unroll
        for (int off = 32; off >= 1; off >>= 1) {
            u32 v2 = __shfl_xor(best, off, 64);
            int p2 = __shfl_xor(bpos, off, 64);
            if (v2 > best) { best = v2; bpos = p2; }
        }
        if (lane == 0) {
            selid[k] = (bpos >= 0) ? (int)(best & 0xFFFFu) : -1;
            if (bpos >= 0) keys[bpos] = 0u;
        }
        __syncthreads();
    }

    // exact fp32 dots for the TK selected candidates (batched 4-wide)
    float xr[8];
    {
        const float4* xp = (const float4*)(x + (size_t)row * DD);
        float4 a = xp[lane * 2], b = xp[lane * 2 + 1];
        xr[0] = a.x; xr[1] = a.y; xr[2] = a.z; xr[3] = a.w;
        xr[4] = b.x; xr[5] = b.y; xr[6] = b.z; xr[7] = b.w;
    }
    for (int s0 = 0; s0 < TK; s0 += 4) {
        int idv[4];
        float4 a0[4], a1[4];
#pragma unroll
        for (int j = 0; j < 4; ++j) {
            idv[j] = selid[s0 + j];                    // wave-uniform
            const int rid = idv[j] >= 0 ? idv[j] : 0;
            const float4* mp = (const float4*)(mu + (size_t)rid * DD);
            a0[j] = mp[lane * 2];
            a1[j] = mp[lane * 2 + 1];
        }
        float d[4];
#pragma unroll
        for (int j = 0; j < 4; ++j)
            d[j] = xr[0] * a0[j].x + xr[1] * a0[j].y + xr[2] * a0[j].z + xr[3] * a0[j].w
                 + xr[4] * a1[j].x + xr[5] * a1[j].y + xr[6] * a1[j].z + xr[7] * a1[j].w;
#pragma unroll
        for (int j = 0; j < 4; ++j) {
#pragma unroll
            for (int off = 32; off >= 1; off >>= 1) d[j] += __shfl_xor(d[j], off, 64);
            if (lane == 0) selex[s0 + j] = (idv[j] >= 0) ? d[j] : -INFINITY;
        }
    }
    __syncthreads();

    float v = selex[lane];
    const int id = selid[lane];
    bool alive = (id >= 0);

    // drop the 32 smallest exact values -> exact top-32 remains
    for (int rdrop = 0; rdrop < 32; ++rdrop) {
        float mn = alive ? v : INFINITY;
        int  mp2 = alive ? lane : 64;
#pragma unroll
        for (int off = 32; off >= 1; off >>= 1) {
            float m2 = __shfl_xor(mn, off, 64);
            int   p2 = __shfl_xor(mp2, off, 64);
            if (m2 < mn || (m2 == mn && p2 < mp2)) { mn = m2; mp2 = p2; }
        }
        if (lane == mp2) alive = false;
    }

    const float dv = alive ? v : -INFINITY;

    // top-1 / top-2 exact values (u, v of the reference)
    float m1 = dv; int p1 = alive ? lane : 64;
#pragma unroll
    for (int off = 32; off >= 1; off >>= 1) {
        float m2 = __shfl_xor(m1, off, 64);
        int   p2 = __shfl_xor(p1, off, 64);
        if (m2 > m1 || (m2 == m1 && p2 < p1)) { m1 = m2; p1 = p2; }
    }
    const float uu = m1;
    float s1 = (lane == p1) ? -INFINITY : dv;
#pragma unroll
    for (int off = 32; off >= 1; off >>= 1) s1 = fmaxf(s1, __shfl_xor(s1, off, 64));
    const float vv = s1;

    const int gid = alive ? id : 0;
    const float av = alpha[gid];
    const float kv = kappa[gid];
    float imp = alive ? fmaxf(kv, 1e-4f) : 0.f;
    float simp = imp;
#pragma unroll
    for (int off = 32; off >= 1; off >>= 1) simp += __shfl_xor(simp, off, 64);
    float w = fmaxf(imp / simp, 1e-8f);
    float tk = alive ? (av * (dv - 1.0f) * 10.0f + logf(w)) : -INFINITY;
    float mx = tk;
#pragma unroll
    for (int off = 32; off >= 1; off >>= 1) mx = fmaxf(mx, __shfl_xor(mx, off, 64));
    float se = alive ? expf(tk - mx) : 0.f;
#pragma unroll
    for (int off = 32; off >= 1; off >>= 1) se += __shfl_xor(se, off, 64);

    if (lane == 0) {
        float esplat = -(mx + logf(se));
        float z = Ww[0] * uu + Ww[1] * vv + Ww[2] * uu * vv + Wb[0];
        float ecomp = 1.f / (1.f + expf(-z));
        out[row] = esplat + 0.1f * egeom[0] + 0.1f * ecomp;
    }
}

extern "C" void kernel_launch(void* const* d_in, const int* in_sizes, int n_in,
                              void* d_out, int out_size, void* d_ws, size_t ws_size,
                              hipStream_t stream)
{
    const float* x     = (const float*)d_in[0];
    const float* mu    = (const float*)d_in[1];
    const float* alpha = (const float*)d_in[2];
    const float* kappa = (const float*)d_in[3];
    const float* Ww    = (const float*)d_in[4];
    const float* Wb    = (const float*)d_in[5];
    float* out = (float*)d_out;

    char* ws = (char*)d_ws;
    u32*   cnt     = (u32*)ws;
    float* partial = (float*)(ws + 16384);
    float* egeom   = (float*)(ws + 32768);
    char*  xi8     = (char*)(ws + 65536);
    char*  mui8    = (char*)(ws + 65536 + 2097152);
    u32*   cand    = (u32*)(ws + 65536 + 2097152 + 25600000);

    hipMemsetAsync(cnt, 0, NR * sizeof(u32), stream);

    k_quant<<<(NR * DD / 8 + 255) / 256, 256, 0, stream>>>(x, xi8, NR * DD / 8);
    k_quant<<<(MM * DD / 8 + 255) / 256, 256, 0, stream>>>(mu, mui8, MM * DD / 8);

    dim3 g1(NR / 256, (MM + 255) / 256);   // 16 x 196 = 3136 = 8 x 392
    k_gemm_topk<<<g1, 512, 0, stream>>>(xi8, mui8, cnt, cand);

    dim3 g2(32, 32);
    k_geom<<<g2, 256, 0, stream>>>(xi8, partial);

    k_reduce_geom<<<1, 1024, 0, stream>>>(partial, egeom);

    k_finalize<<<NR, 64, 0, stream>>>(cand, cnt, x, mu, alpha, kappa, Ww, Wb, egeom, out);
}

// Round 13
// 414.473 us; speedup vs baseline: 1.1964x; 1.1169x over previous
//
#include <hip/hip_runtime.h>
#include <math.h>

#define NR 4096
#define DD 512
#define MM 50000
#define RCAP 64
#define TK 64
#define T0 0.127f
#define QS 400.0f
#define QINV (1.0f / 160000.0f)

typedef unsigned int u32;
typedef unsigned short u16;
typedef int i32x4 __attribute__((ext_vector_type(4)));

#define AS1 __attribute__((address_space(1)))
#define AS3 __attribute__((address_space(3)))

__device__ __forceinline__ u16 f2bf(float f) {
    u32 u = __float_as_uint(f);
    u32 r = (u + 0x7FFFu + ((u >> 16) & 1u)) >> 16;   // RNE
    return (u16)r;
}

// ---------------- ws layout ----------------
// [0, 131072)              cnt2 (8 regions x 4096 u32) -- zeroed each launch
// [131072, 135168)         geom partials (1024 f32, fully written)
// [135168, 135172)         e_geom scalar
// [262144, +2MB)           xi8  (4096x512 int8, scale 400)
// [+2MB, +27.6MB)          mui8 (50000x512 int8)
// [+27.6MB, +36MB)         cand2 (8 x 4096 x 64 u32 = {bf16val:16, idx:16})
//   region g = blockdispatch&7: XCD-private pushes (no cross-XCD line thrash)

// ============ int8 symmetric quantization (RNE, scale 400) ============
__global__ __launch_bounds__(256) void k_quant(const float* __restrict__ src,
                                               char* __restrict__ dst, int n8) {
    int i = blockIdx.x * 256 + threadIdx.x;
    if (i >= n8) return;
    const float4* s4 = (const float4*)src;
    float4 a = s4[(size_t)i * 2], b = s4[(size_t)i * 2 + 1];
    float v[8] = {a.x, a.y, a.z, a.w, b.x, b.y, b.z, b.w};
    u32 lo = 0, hi = 0;
#pragma unroll
    for (int j = 0; j < 4; ++j) {
        int q = __float2int_rn(v[j] * QS);
        q = q > 127 ? 127 : (q < -127 ? -127 : q);
        lo |= ((u32)(unsigned char)(char)q) << (8 * j);
    }
#pragma unroll
    for (int j = 0; j < 4; ++j) {
        int q = __float2int_rn(v[4 + j] * QS);
        q = q > 127 ? 127 : (q < -127 ? -127 : q);
        hi |= ((u32)(unsigned char)(char)q) << (8 * j);
    }
    *(uint2*)(dst + (size_t)i * 8) = make_uint2(lo, hi);
}

// ============ i8 MFMA GEMM x @ mu^T, 128x128 tile (R10 structure) ============
// Single 32 KB buffer, 5 blocks/CU, plain 2-syncthreads K-loop (best measured).
// Push path: region-indexed (g = d&7) XCD-private counters + slots.
__global__ __launch_bounds__(256, 5) void k_gemm_topk(
    const char* __restrict__ xi8, const char* __restrict__ mui8,
    u32* __restrict__ cnt2, u32* __restrict__ cand2)
{
    __shared__ char smem[32768];          // A 16KB | B 16KB

    const int t = threadIdx.x;
    const int lane = t & 63;
    const int wid = t >> 6;
    const int wr = wid >> 1, wc = wid & 1;
    const int fr = lane & 15, fq = lane >> 4;

    // ---- XCD-aware bijective remap (12512 blocks = 8 x 1564) ----
    const u32 d   = (u32)blockIdx.y * (u32)gridDim.x + (u32)blockIdx.x;
    const u32 g   = d & 7u;               // region / XCD class
    const u32 p   = g * 1564u + (d >> 3);
    const int r0  = (int)(p & 31u) * 128;     // row-panel (fastest)
    const int c0  = (int)(p >> 5) * 128;      // col-panel (class-contiguous)

    i32x4 acc[4][4];
#pragma unroll
    for (int m = 0; m < 4; ++m)
#pragma unroll
        for (int n = 0; n < 4; ++n) acc[m][n] = (i32x4){0, 0, 0, 0};

    for (int kt = 0; kt < DD; kt += 128) {
        __syncthreads();                  // previous tile fully consumed
#pragma unroll
        for (int i = 0; i < 4; ++i) {
            const int L  = i * 4096 + t * 16;
            const int rw = L >> 7;                 // 0..127 (128-B rows)
            const int cb = (L & 127) ^ ((rw & 7) << 4);
            const char* srcA = xi8 + (size_t)(r0 + rw) * DD + kt + cb;
            __builtin_amdgcn_global_load_lds((const AS1 u32*)srcA, (AS3 u32*)(smem + L), 16, 0, 0);
            int gr = c0 + rw; if (gr > MM - 1) gr = MM - 1;   // clamp, filtered at push
            const char* srcB = mui8 + (size_t)gr * DD + kt + cb;
            __builtin_amdgcn_global_load_lds((const AS1 u32*)srcB, (AS3 u32*)(smem + 16384 + L), 16, 0, 0);
        }
        __syncthreads();                  // staged tile visible (vmcnt drained)
#pragma unroll
        for (int kk = 0; kk < 2; ++kk) {  // two K=64 halves of BK=128
            i32x4 af[4], bfr[4];
#pragma unroll
            for (int m = 0; m < 4; ++m) {
                const int ra = wr * 64 + m * 16 + fr;
                af[m] = *(const i32x4*)(smem + ((ra << 7) | ((kk * 64 + fq * 16) ^ ((ra & 7) << 4))));
            }
#pragma unroll
            for (int n = 0; n < 4; ++n) {
                const int rb = wc * 64 + n * 16 + fr;
                bfr[n] = *(const i32x4*)(smem + 16384 + ((rb << 7) | ((kk * 64 + fq * 16) ^ ((rb & 7) << 4))));
            }
#pragma unroll
            for (int m = 0; m < 4; ++m)
#pragma unroll
                for (int n = 0; n < 4; ++n)
                    acc[m][n] = __builtin_amdgcn_mfma_i32_16x16x64_i8(af[m], bfr[n], acc[m][n], 0, 0, 0);
        }
    }

    // C/D layout (m89): col = lane&15, row = (lane>>4)*4 + reg
    // Push to XCD-private region g.
#pragma unroll
    for (int m = 0; m < 4; ++m) {
        const int rowb = r0 + wr * 64 + m * 16 + fq * 4;
#pragma unroll
        for (int n = 0; n < 4; ++n) {
            const int col = c0 + wc * 64 + n * 16 + fr;
#pragma unroll
            for (int r = 0; r < 4; ++r) {
                const float v = (float)acc[m][n][r] * QINV;
                if (v >= T0 && col < MM) {
                    const u32 slot = g * NR + (u32)(rowb + r);
                    u32 pos = atomicAdd(&cnt2[slot], 1u);
                    if (pos < RCAP)
                        cand2[(size_t)slot * RCAP + pos] =
                            (((u32)f2bf(v)) << 16) | (u32)col;
                }
            }
        }
    }
}

// ============ x @ x^T geometric energy (R10's proven 128^2 form) ============
__global__ __launch_bounds__(256, 5) void k_geom(
    const char* __restrict__ xi8, float* __restrict__ partial)
{
    const int bx = blockIdx.x, by = blockIdx.y;
    const int t = threadIdx.x;
    if (bx < by) { if (t == 0) partial[by * 32 + bx] = 0.f; return; }

    __shared__ char smem[32768];
    __shared__ float red[4];

    const int lane = t & 63;
    const int wid = t >> 6;
    const int wr = wid >> 1, wc = wid & 1;
    const int fr = lane & 15, fq = lane >> 4;
    const int r0 = by * 128;
    const int c0 = bx * 128;

    i32x4 acc[4][4];
#pragma unroll
    for (int m = 0; m < 4; ++m)
#pragma unroll
        for (int n = 0; n < 4; ++n) acc[m][n] = (i32x4){0, 0, 0, 0};

    for (int kt = 0; kt < DD; kt += 128) {
        __syncthreads();
#pragma unroll
        for (int i = 0; i < 4; ++i) {
            const int L  = i * 4096 + t * 16;
            const int rw = L >> 7;
            const int cb = (L & 127) ^ ((rw & 7) << 4);
            const char* srcA = xi8 + (size_t)(r0 + rw) * DD + kt + cb;
            __builtin_amdgcn_global_load_lds((const AS1 u32*)srcA, (AS3 u32*)(smem + L), 16, 0, 0);
            const char* srcB = xi8 + (size_t)(c0 + rw) * DD + kt + cb;
            __builtin_amdgcn_global_load_lds((const AS1 u32*)srcB, (AS3 u32*)(smem + 16384 + L), 16, 0, 0);
        }
        __syncthreads();
#pragma unroll
        for (int kk = 0; kk < 2; ++kk) {
            i32x4 af[4], bfr[4];
#pragma unroll
            for (int m = 0; m < 4; ++m) {
                const int ra = wr * 64 + m * 16 + fr;
                af[m] = *(const i32x4*)(smem + ((ra << 7) | ((kk * 64 + fq * 16) ^ ((ra & 7) << 4))));
            }
#pragma unroll
            for (int n = 0; n < 4; ++n) {
                const int rb = wc * 64 + n * 16 + fr;
                bfr[n] = *(const i32x4*)(smem + 16384 + ((rb << 7) | ((kk * 64 + fq * 16) ^ ((rb & 7) << 4))));
            }
#pragma unroll
            for (int m = 0; m < 4; ++m)
#pragma unroll
                for (int n = 0; n < 4; ++n)
                    acc[m][n] = __builtin_amdgcn_mfma_i32_16x16x64_i8(af[m], bfr[n], acc[m][n], 0, 0, 0);
        }
    }

    float local = 0.f;
#pragma unroll
    for (int m = 0; m < 4; ++m) {
        const int rowb = r0 + wr * 64 + m * 16 + fq * 4;
#pragma unroll
        for (int n = 0; n < 4; ++n) {
            const int col = c0 + wc * 64 + n * 16 + fr;
#pragma unroll
            for (int r = 0; r < 4; ++r) {
                if (rowb + r != col) {
                    float s = fminf((float)acc[m][n][r] * QINV, 0.9999f);
                    local += -logf(1.0f - s + 1e-4f);
                }
            }
        }
    }
    if (bx > by) local *= 2.f;   // symmetric half counted twice

#pragma unroll
    for (int off = 32; off >= 1; off >>= 1) local += __shfl_xor(local, off, 64);
    if (lane == 0) red[wid] = local;
    __syncthreads();
    if (t == 0) partial[by * 32 + bx] = red[0] + red[1] + red[2] + red[3];
}

__global__ void k_reduce_geom(const float* __restrict__ partial, float* __restrict__ egeom)
{
    __shared__ float red[16];
    const int t = threadIdx.x;
    float v = partial[t];
#pragma unroll
    for (int off = 32; off >= 1; off >>= 1) v += __shfl_xor(v, off, 64);
    const int wave = t >> 6, lane = t & 63;
    if (lane == 0) red[wave] = v;
    __syncthreads();
    if (t == 0) {
        float s = 0.f;
        for (int i = 0; i < 16; ++i) s += red[i];
        egeom[0] = s / ((float)NR * (float)(NR - 1));
    }
}

// ===== finalize: 1 wave per row. merge 8 regions -> top-64 by key ->
// exact fp32 recompute -> top-32 -> epilogue =====
__global__ __launch_bounds__(64) void k_finalize(
    const u32* __restrict__ cand2, const u32* __restrict__ cnt2,
    const float* __restrict__ x, const float* __restrict__ mu,
    const float* __restrict__ alpha, const float* __restrict__ kappa,
    const float* __restrict__ Ww, const float* __restrict__ Wb,
    const float* __restrict__ egeom, float* __restrict__ out)
{
    __shared__ u32   keys[8 * RCAP];
    __shared__ int   selid[TK];
    __shared__ float selex[TK];

    const int lane = threadIdx.x;
    const int row = blockIdx.x;

    int total = 0;
#pragma unroll
    for (int g = 0; g < 8; ++g) {
        const u32 slot = (u32)g * NR + (u32)row;
        int cg = (int)cnt2[slot];
        if (cg > RCAP) cg = RCAP;
        if (lane < cg)
            keys[total + lane] = cand2[(size_t)slot * RCAP + lane];
        total += cg;
    }
    const int c = total;                   // wave-uniform, <= 512
    __syncthreads();

    // iterative argmax: top-TK keys (keys globally distinct: col embedded)
    for (int k = 0; k < TK; ++k) {
        u32 best = 0u; int bpos = -1;
        for (int s = lane; s < c; s += 64) {
            u32 v = keys[s];
            if (v > best) { best = v; bpos = s; }
        }
#pragma unroll
        for (int off = 32; off >= 1; off >>= 1) {
            u32 v2 = __shfl_xor(best, off, 64);
            int p2 = __shfl_xor(bpos, off, 64);
            if (v2 > best) { best = v2; bpos = p2; }
        }
        if (lane == 0) {
            selid[k] = (bpos >= 0) ? (int)(best & 0xFFFFu) : -1;
            if (bpos >= 0) keys[bpos] = 0u;
        }
        __syncthreads();
    }

    // exact fp32 dots for the TK selected candidates (batched 4-wide)
    float xr[8];
    {
        const float4* xp = (const float4*)(x + (size_t)row * DD);
        float4 a = xp[lane * 2], b = xp[lane * 2 + 1];
        xr[0] = a.x; xr[1] = a.y; xr[2] = a.z; xr[3] = a.w;
        xr[4] = b.x; xr[5] = b.y; xr[6] = b.z; xr[7] = b.w;
    }
    for (int s0 = 0; s0 < TK; s0 += 4) {
        int idv[4];
        float4 a0[4], a1[4];
#pragma unroll
        for (int j = 0; j < 4; ++j) {
            idv[j] = selid[s0 + j];                    // wave-uniform
            const int rid = idv[j] >= 0 ? idv[j] : 0;
            const float4* mp = (const float4*)(mu + (size_t)rid * DD);
            a0[j] = mp[lane * 2];
            a1[j] = mp[lane * 2 + 1];
        }
        float d[4];
#pragma unroll
        for (int j = 0; j < 4; ++j)
            d[j] = xr[0] * a0[j].x + xr[1] * a0[j].y + xr[2] * a0[j].z + xr[3] * a0[j].w
                 + xr[4] * a1[j].x + xr[5] * a1[j].y + xr[6] * a1[j].z + xr[7] * a1[j].w;
#pragma unroll
        for (int j = 0; j < 4; ++j) {
#pragma unroll
            for (int off = 32; off >= 1; off >>= 1) d[j] += __shfl_xor(d[j], off, 64);
            if (lane == 0) selex[s0 + j] = (idv[j] >= 0) ? d[j] : -INFINITY;
        }
    }
    __syncthreads();

    float v = selex[lane];
    const int id = selid[lane];
    bool alive = (id >= 0);

    // drop the 32 smallest exact values -> exact top-32 remains
    for (int rdrop = 0; rdrop < 32; ++rdrop) {
        float mn = alive ? v : INFINITY;
        int  mp2 = alive ? lane : 64;
#pragma unroll
        for (int off = 32; off >= 1; off >>= 1) {
            float m2 = __shfl_xor(mn, off, 64);
            int   p2 = __shfl_xor(mp2, off, 64);
            if (m2 < mn || (m2 == mn && p2 < mp2)) { mn = m2; mp2 = p2; }
        }
        if (lane == mp2) alive = false;
    }

    const float dv = alive ? v : -INFINITY;

    // top-1 / top-2 exact values (u, v of the reference)
    float m1 = dv; int p1 = alive ? lane : 64;
#pragma unroll
    for (int off = 32; off >= 1; off >>= 1) {
        float m2 = __shfl_xor(m1, off, 64);
        int   p2 = __shfl_xor(p1, off, 64);
        if (m2 > m1 || (m2 == m1 && p2 < p1)) { m1 = m2; p1 = p2; }
    }
    const float uu = m1;
    float s1 = (lane == p1) ? -INFINITY : dv;
#pragma unroll
    for (int off = 32; off >= 1; off >>= 1) s1 = fmaxf(s1, __shfl_xor(s1, off, 64));
    const float vv = s1;

    const int gid = alive ? id : 0;
    const float av = alpha[gid];
    const float kv = kappa[gid];
    float imp = alive ? fmaxf(kv, 1e-4f) : 0.f;
    float simp = imp;
#pragma unroll
    for (int off = 32; off >= 1; off >>= 1) simp += __shfl_xor(simp, off, 64);
    float w = fmaxf(imp / simp, 1e-8f);
    float tk = alive ? (av * (dv - 1.0f) * 10.0f + logf(w)) : -INFINITY;
    float mx = tk;
#pragma unroll
    for (int off = 32; off >= 1; off >>= 1) mx = fmaxf(mx, __shfl_xor(mx, off, 64));
    float se = alive ? expf(tk - mx) : 0.f;
#pragma unroll
    for (int off = 32; off >= 1; off >>= 1) se += __shfl_xor(se, off, 64);

    if (lane == 0) {
        float esplat = -(mx + logf(se));
        float z = Ww[0] * uu + Ww[1] * vv + Ww[2] * uu * vv + Wb[0];
        float ecomp = 1.f / (1.f + expf(-z));
        out[row] = esplat + 0.1f * egeom[0] + 0.1f * ecomp;
    }
}

extern "C" void kernel_launch(void* const* d_in, const int* in_sizes, int n_in,
                              void* d_out, int out_size, void* d_ws, size_t ws_size,
                              hipStream_t stream)
{
    const float* x     = (const float*)d_in[0];
    const float* mu    = (const float*)d_in[1];
    const float* alpha = (const float*)d_in[2];
    const float* kappa = (const float*)d_in[3];
    const float* Ww    = (const float*)d_in[4];
    const float* Wb    = (const float*)d_in[5];
    float* out = (float*)d_out;

    char* ws = (char*)d_ws;
    u32*   cnt2    = (u32*)ws;                          // 128 KB
    float* partial = (float*)(ws + 131072);
    float* egeom   = (float*)(ws + 135168);
    char*  xi8     = (char*)(ws + 262144);
    char*  mui8    = (char*)(ws + 262144 + 2097152);
    u32*   cand2   = (u32*)(ws + 262144 + 2097152 + 25600000);

    hipMemsetAsync(cnt2, 0, 8 * NR * sizeof(u32), stream);

    k_quant<<<(NR * DD / 8 + 255) / 256, 256, 0, stream>>>(x, xi8, NR * DD / 8);
    k_quant<<<(MM * DD / 8 + 255) / 256, 256, 0, stream>>>(mu, mui8, MM * DD / 8);

    dim3 g1(NR / 128, (MM + 127) / 128);   // 32 x 391 = 12512 = 8 x 1564
    k_gemm_topk<<<g1, 256, 0, stream>>>(xi8, mui8, cnt2, cand2);

    dim3 g2(32, 32);
    k_geom<<<g2, 256, 0, stream>>>(xi8, partial);

    k_reduce_geom<<<1, 1024, 0, stream>>>(partial, egeom);

    k_finalize<<<NR, 64, 0, stream>>>(cand2, cnt2, x, mu, alpha, kappa, Ww, Wb, egeom, out);
}